// Round 5
// baseline (236.523 us; speedup 1.0000x reference)
//
#include <hip/hip_runtime.h>
#include <stdint.h>

#define N 8192
#define Dq 64
#define SPLITS 32          // 256 cand-tiles / 32 = 8 tiles/wave; 64*32=2048 blocks = 8/CU
#define MARGIN 0.5f

typedef __attribute__((ext_vector_type(8))) short short8;     // 8 bf16 (4 VGPRs)
typedef __attribute__((ext_vector_type(16))) float floatx16;  // 32x32 MFMA accumulator

__device__ __forceinline__ unsigned short f2bf(float f) {
  unsigned u = __float_as_uint(f);
  u += 0x7FFF + ((u >> 16) & 1);   // round-to-nearest-even
  return (unsigned short)(u >> 16);
}

// Kernel 1: fp32 -> bf16 convert into FRAGMENT-READY tiled layout + aug-norm
// encode. Layout: embF[tile t][chunk c][lane l] (16B) where lane l gets row
// t*32+(l&31), shorts (l>>5)*8 + c*16 .. +7. A wave's chunk-c fragment load is
// then embF + t*2048 + c*512 + l*8 shorts — perfectly coalesced.
// One thread per 8 floats (N*8 threads); norm butterfly over 8 lanes.
__global__ __launch_bounds__(256) void prep_kernel(
    const float* __restrict__ emb,
    unsigned short* __restrict__ embF, unsigned short* __restrict__ sqb,
    float* __restrict__ out) {
  int tid = blockIdx.x * 256 + threadIdx.x;     // N*8 threads
  int row = tid >> 3;
  int m = tid & 7;                               // chunk-of-8-shorts index
  const float4* src = reinterpret_cast<const float4*>(emb) + (size_t)row * 16 + m * 2;
  float4 v0 = src[0], v1 = src[1];
  float s = v0.x * v0.x + v0.y * v0.y + v0.z * v0.z + v0.w * v0.w
          + v1.x * v1.x + v1.y * v1.y + v1.z * v1.z + v1.w * v1.w;
  #pragma unroll
  for (int off = 1; off < 8; off <<= 1) s += __shfl_xor(s, off);
  if (m == 0) sqb[row] = f2bf(-(0.5f * s + 2.0f));
  short8 b;
  b[0] = (short)f2bf(v0.x); b[1] = (short)f2bf(v0.y);
  b[2] = (short)f2bf(v0.z); b[3] = (short)f2bf(v0.w);
  b[4] = (short)f2bf(v1.x); b[5] = (short)f2bf(v1.y);
  b[6] = (short)f2bf(v1.z); b[7] = (short)f2bf(v1.w);
  // chunk m covers k = m*8..m*8+7  ->  c = m>>1, half = m&1
  size_t dst = (size_t)(row >> 5) * 2048 + (size_t)(m >> 1) * 512
             + (size_t)((m & 1) * 32 + (row & 31)) * 8;
  *reinterpret_cast<short8*>(embF + dst) = b;
  if (tid == 0) out[0] = 0.f;
}

// Kernel 2: batch-hard mining, 32x32 tiles, fragment-ready coalesced loads.
// acc = dot - 0.5(sq_i+sq_j) - 4 = -(d/2+4) < 0 via 5th augmented MFMA; for
// all-negative floats u32 bits are monotone INCREASING in d, so
// key = (bits(acc)&~0x1FFF)|idx13 gives argmax(d)=u32max, argmin(d)=u32min.
// Per-split winners stored plainly; finalize combines splits (keys make the
// cross-split tie-break automatic: jinv for max -> smaller j, j for min).
// 8 waves/SIMD (2048 blocks = 8 blocks/CU) to hide L2 + MFMA + epilogue deps.
__global__ __launch_bounds__(256, 8) void mine_kernel(
    const unsigned short* __restrict__ embF,
    const unsigned short* __restrict__ sqb, const int* __restrict__ cls,
    unsigned* __restrict__ pmax, unsigned* __restrict__ pmin) {
  const int lane = threadIdx.x & 63;
  const int wave = threadIdx.x >> 6;
  const int lo = lane & 31;
  const int half = lane >> 5;
  const int aT = blockIdx.x * 4 + wave;          // anchor tile 0..255
  const int rowBase = aT * 32;
  const int split = blockIdx.y;
  const int tBase = split * (256 / SPLITS);

  const short8* fr = reinterpret_cast<const short8*>(embF);
  // A fragments: chunk c at fr[tile*256 + c*64 + lane]  (coalesced)
  const short8* ea = fr + (size_t)aT * 256 + lane;
  short8 a0 = ea[0], a1 = ea[64], a2 = ea[128], a3 = ea[192];
  // Aug A frag: A'[m][0]=1.0, A'[m][1]=-(0.5*sq_m+2) (pre-encoded bf16).
  unsigned short sqm = sqb[rowBase + lo];
  const short one = (short)0x3F80;               // bf16 1.0
  short8 a4 = {(short)(half == 0 ? one : 0),
               (short)(half == 0 ? (short)sqm : 0), 0, 0, 0, 0, 0, 0};

  // C/D layout: col = lane&31, row = (reg&3) + 8*(reg>>2) + 4*half.
  int ci[16];
  #pragma unroll
  for (int r = 0; r < 16; ++r)
    ci[r] = cls[rowBase + (r & 3) + 8 * (r >> 2) + 4 * half];

  floatx16 zacc;
  #pragma unroll
  for (int i = 0; i < 16; ++i) zacc[i] = 0.f;

  unsigned maxk[16], mink[16];
  #pragma unroll
  for (int r = 0; r < 16; ++r) { maxk[r] = 0u; mink[r] = 0xFFFFFFFFu; }

  #pragma unroll 2
  for (int t = tBase; t < tBase + 256 / SPLITS; ++t) {
    const int cb = t * 32;
    const short8* eb = fr + (size_t)t * 256 + lane;
    short8 b0 = eb[0], b1 = eb[64], b2 = eb[128], b3 = eb[192];
    unsigned short sqn = sqb[cb + lo];
    int cj = cls[cb + lo];
    short8 b4 = {(short)(half == 0 ? (short)sqn : 0),
                 (short)(half == 0 ? one : 0), 0, 0, 0, 0, 0, 0};

    floatx16 acc = __builtin_amdgcn_mfma_f32_32x32x16_bf16(a0, b0, zacc, 0, 0, 0);
    acc = __builtin_amdgcn_mfma_f32_32x32x16_bf16(a1, b1, acc, 0, 0, 0);
    acc = __builtin_amdgcn_mfma_f32_32x32x16_bf16(a2, b2, acc, 0, 0, 0);
    acc = __builtin_amdgcn_mfma_f32_32x32x16_bf16(a3, b3, acc, 0, 0, 0);
    acc = __builtin_amdgcn_mfma_f32_32x32x16_bf16(a4, b4, acc, 0, 0, 0);

    const unsigned j = cb + lo;
    const unsigned jinv = 8191u - j;
    #pragma unroll
    for (int r = 0; r < 16; ++r) {
      unsigned kb = __float_as_uint(acc[r]) & 0xFFFFE000u;
      bool same = (ci[r] == cj);
      unsigned kp = same ? (kb | jinv) : 0u;
      unsigned kn = same ? 0xFFFFFFFFu : (kb | j);
      maxk[r] = maxk[r] > kp ? maxk[r] : kp;
      mink[r] = mink[r] < kn ? mink[r] : kn;
    }
  }

  // Column reduction within each 32-lane half (xor masks 1..16 stay in-half).
  #pragma unroll
  for (int off = 1; off < 32; off <<= 1) {
    #pragma unroll
    for (int r = 0; r < 16; ++r) {
      unsigned om = (unsigned)__shfl_xor((int)maxk[r], off);
      maxk[r] = maxk[r] > om ? maxk[r] : om;
      unsigned on = (unsigned)__shfl_xor((int)mink[r], off);
      mink[r] = mink[r] < on ? mink[r] : on;
    }
  }

  if (lo == 0) {
    #pragma unroll
    for (int r = 0; r < 16; ++r) {
      int row = rowBase + (r & 3) + 8 * (r >> 2) + 4 * half;
      pmax[split * N + row] = maxk[r];
      pmin[split * N + row] = mink[r];
    }
  }
}

// Kernel 3: combine split keys (u32 max/min), decode indices, recompute ap/an
// in fp32 from ORIGINAL embeddings (matches reference), relu+margin, mean.
// 4 lanes per anchor, each handles 16 of the 64 dims.
__global__ __launch_bounds__(256) void finalize_kernel(
    const float* __restrict__ emb,
    const unsigned* __restrict__ pmax, const unsigned* __restrict__ pmin,
    float* __restrict__ out) {
  int tid = blockIdx.x * 256 + threadIdx.x;   // N*4 threads
  int anchor = tid >> 2;
  int part = tid & 3;
  unsigned Kp = 0u, Kn = 0xFFFFFFFFu;
  #pragma unroll
  for (int s = 0; s < SPLITS; ++s) {
    unsigned vp = pmax[s * N + anchor];
    Kp = Kp > vp ? Kp : vp;
    unsigned vn = pmin[s * N + anchor];
    Kn = Kn < vn ? Kn : vn;
  }
  int jp = 8191 - (int)(Kp & 8191u);
  int jn = (int)(Kn & 8191u);

  const float4* xi = reinterpret_cast<const float4*>(emb + (size_t)anchor * Dq) + part * 4;
  const float4* xp = reinterpret_cast<const float4*>(emb + (size_t)jp * Dq) + part * 4;
  const float4* xn = reinterpret_cast<const float4*>(emb + (size_t)jn * Dq) + part * 4;
  float ap = 0.f, an = 0.f;
  #pragma unroll
  for (int k = 0; k < 4; ++k) {
    float4 a = xi[k], p = xp[k], q = xn[k];
    float dx = a.x - p.x, dy = a.y - p.y, dz = a.z - p.z, dw = a.w - p.w;
    ap += dx * dx + dy * dy + dz * dz + dw * dw;
    dx = a.x - q.x; dy = a.y - q.y; dz = a.z - q.z; dw = a.w - q.w;
    an += dx * dx + dy * dy + dz * dz + dw * dw;
  }
  #pragma unroll
  for (int off = 1; off < 4; off <<= 1) {
    ap += __shfl_xor(ap, off);
    an += __shfl_xor(an, off);
  }
  float loss = (part == 0) ? fmaxf(ap - an + MARGIN, 0.f) : 0.f;
  #pragma unroll
  for (int off = 4; off < 64; off <<= 1) loss += __shfl_xor(loss, off);
  __shared__ float wsum[4];
  if ((threadIdx.x & 63) == 0) wsum[threadIdx.x >> 6] = loss;
  __syncthreads();
  if (threadIdx.x == 0)
    atomicAdd(out, (wsum[0] + wsum[1] + wsum[2] + wsum[3]) * (1.0f / (float)N));
}

extern "C" void kernel_launch(void* const* d_in, const int* in_sizes, int n_in,
                              void* d_out, int out_size, void* d_ws, size_t ws_size,
                              hipStream_t stream) {
  const float* emb = (const float*)d_in[0];
  const int* tgt = (const int*)d_in[1];   // int32 on device (verified R1-R4)
  float* out = (float*)d_out;

  char* ws = (char*)d_ws;
  unsigned short* embF = (unsigned short*)ws;                       // 1 MB tiled bf16
  unsigned short* sqb = (unsigned short*)(ws + (size_t)N * Dq * 2); // 16 KB
  unsigned* pmax = (unsigned*)(ws + (size_t)N * Dq * 2 + N * 2);    // 1 MB
  unsigned* pmin = pmax + (size_t)SPLITS * N;                       // 1 MB

  prep_kernel<<<N * 8 / 256, 256, 0, stream>>>(emb, embF, sqb, out);
  mine_kernel<<<dim3(N / 128, SPLITS), 256, 0, stream>>>(embF, sqb, tgt, pmax, pmin);
  finalize_kernel<<<N * 4 / 256, 256, 0, stream>>>(emb, pmax, pmin, out);
}

// Round 6
// 125.330 us; speedup vs baseline: 1.8872x; 1.8872x over previous
//
#include <hip/hip_runtime.h>
#include <stdint.h>

#define N 8192
#define Dq 64
#define SPLITS 24          // 64*24 = 1536 blocks = exactly 6 blocks/CU resident
#define MARGIN 0.5f

typedef __attribute__((ext_vector_type(8))) short short8;     // 8 bf16 (4 VGPRs)
typedef __attribute__((ext_vector_type(16))) float floatx16;  // 32x32 MFMA accumulator

__device__ __forceinline__ unsigned short f2bf(float f) {
  unsigned u = __float_as_uint(f);
  u += 0x7FFF + ((u >> 16) & 1);   // round-to-nearest-even
  return (unsigned short)(u >> 16);
}

// Kernel 1: fp32 -> bf16 convert into FRAGMENT-READY tiled layout + aug-norm
// encode. Layout: embF[tile t][chunk c][lane l] (16B) where lane l gets row
// t*32+(l&31), shorts (l>>5)*8 + c*16 .. +7. A wave's chunk-c fragment load is
// then embF + t*2048 + c*512 + l*8 shorts — perfectly coalesced.
__global__ __launch_bounds__(256) void prep_kernel(
    const float* __restrict__ emb,
    unsigned short* __restrict__ embF, unsigned short* __restrict__ sqb,
    float* __restrict__ out) {
  int tid = blockIdx.x * 256 + threadIdx.x;     // N*8 threads
  int row = tid >> 3;
  int m = tid & 7;                               // chunk-of-8-shorts index
  const float4* src = reinterpret_cast<const float4*>(emb) + (size_t)row * 16 + m * 2;
  float4 v0 = src[0], v1 = src[1];
  float s = v0.x * v0.x + v0.y * v0.y + v0.z * v0.z + v0.w * v0.w
          + v1.x * v1.x + v1.y * v1.y + v1.z * v1.z + v1.w * v1.w;
  #pragma unroll
  for (int off = 1; off < 8; off <<= 1) s += __shfl_xor(s, off);
  if (m == 0) sqb[row] = f2bf(-(0.5f * s + 2.0f));
  short8 b;
  b[0] = (short)f2bf(v0.x); b[1] = (short)f2bf(v0.y);
  b[2] = (short)f2bf(v0.z); b[3] = (short)f2bf(v0.w);
  b[4] = (short)f2bf(v1.x); b[5] = (short)f2bf(v1.y);
  b[6] = (short)f2bf(v1.z); b[7] = (short)f2bf(v1.w);
  // chunk m covers k = m*8..m*8+7  ->  c = m>>1, half = m&1
  size_t dst = (size_t)(row >> 5) * 2048 + (size_t)(m >> 1) * 512
             + (size_t)((m & 1) * 32 + (row & 31)) * 8;
  *reinterpret_cast<short8*>(embF + dst) = b;
  if (tid == 0) out[0] = 0.f;
}

// Kernel 2: batch-hard mining, 32x32 tiles, fragment-ready coalesced loads.
// acc = dot - 0.5(sq_i+sq_j) - 4 = -(d/2+4) < 0 via 5th augmented MFMA; for
// all-negative floats u32 bits are monotone INCREASING in d, so
// key = (bits(acc)&~0x1FFF)|idx13 gives argmax(d)=u32max, argmin(d)=u32min.
// Per-split winners stored plainly; finalize combines splits.
// NOTE: needs ~72 unified VGPR+AGPR regs -> 6 waves/SIMD max (bounds(256,8)
// in R5 forced 64-reg budget and spilled 800 MB of scratch: 42->191 us).
__global__ __launch_bounds__(256, 6) void mine_kernel(
    const unsigned short* __restrict__ embF,
    const unsigned short* __restrict__ sqb, const int* __restrict__ cls,
    unsigned* __restrict__ pmax, unsigned* __restrict__ pmin) {
  const int lane = threadIdx.x & 63;
  const int wave = threadIdx.x >> 6;
  const int lo = lane & 31;
  const int half = lane >> 5;
  const int aT = blockIdx.x * 4 + wave;          // anchor tile 0..255
  const int rowBase = aT * 32;
  const int split = blockIdx.y;
  const int t0 = (256 * split) / SPLITS;
  const int t1 = (256 * (split + 1)) / SPLITS;

  const short8* fr = reinterpret_cast<const short8*>(embF);
  // A fragments: chunk c at fr[tile*256 + c*64 + lane]  (coalesced)
  const short8* ea = fr + (size_t)aT * 256 + lane;
  short8 a0 = ea[0], a1 = ea[64], a2 = ea[128], a3 = ea[192];
  // Aug A frag: A'[m][0]=1.0, A'[m][1]=-(0.5*sq_m+2) (pre-encoded bf16).
  unsigned short sqm = sqb[rowBase + lo];
  const short one = (short)0x3F80;               // bf16 1.0
  short8 a4 = {(short)(half == 0 ? one : 0),
               (short)(half == 0 ? (short)sqm : 0), 0, 0, 0, 0, 0, 0};

  // C/D layout: col = lane&31, row = (reg&3) + 8*(reg>>2) + 4*half.
  int ci[16];
  #pragma unroll
  for (int r = 0; r < 16; ++r)
    ci[r] = cls[rowBase + (r & 3) + 8 * (r >> 2) + 4 * half];

  floatx16 zacc;
  #pragma unroll
  for (int i = 0; i < 16; ++i) zacc[i] = 0.f;

  unsigned maxk[16], mink[16];
  #pragma unroll
  for (int r = 0; r < 16; ++r) { maxk[r] = 0u; mink[r] = 0xFFFFFFFFu; }

  #pragma unroll 2
  for (int t = t0; t < t1; ++t) {
    const int cb = t * 32;
    const short8* eb = fr + (size_t)t * 256 + lane;
    short8 b0 = eb[0], b1 = eb[64], b2 = eb[128], b3 = eb[192];
    unsigned short sqn = sqb[cb + lo];
    int cj = cls[cb + lo];
    short8 b4 = {(short)(half == 0 ? (short)sqn : 0),
                 (short)(half == 0 ? one : 0), 0, 0, 0, 0, 0, 0};

    floatx16 acc = __builtin_amdgcn_mfma_f32_32x32x16_bf16(a0, b0, zacc, 0, 0, 0);
    acc = __builtin_amdgcn_mfma_f32_32x32x16_bf16(a1, b1, acc, 0, 0, 0);
    acc = __builtin_amdgcn_mfma_f32_32x32x16_bf16(a2, b2, acc, 0, 0, 0);
    acc = __builtin_amdgcn_mfma_f32_32x32x16_bf16(a3, b3, acc, 0, 0, 0);
    acc = __builtin_amdgcn_mfma_f32_32x32x16_bf16(a4, b4, acc, 0, 0, 0);

    const unsigned j = cb + lo;
    const unsigned jinv = 8191u - j;
    #pragma unroll
    for (int r = 0; r < 16; ++r) {
      unsigned kb = __float_as_uint(acc[r]) & 0xFFFFE000u;
      bool same = (ci[r] == cj);
      unsigned kp = same ? (kb | jinv) : 0u;
      unsigned kn = same ? 0xFFFFFFFFu : (kb | j);
      maxk[r] = maxk[r] > kp ? maxk[r] : kp;
      mink[r] = mink[r] < kn ? mink[r] : kn;
    }
  }

  // Column reduction within each 32-lane half (xor masks 1..16 stay in-half).
  #pragma unroll
  for (int off = 1; off < 32; off <<= 1) {
    #pragma unroll
    for (int r = 0; r < 16; ++r) {
      unsigned om = (unsigned)__shfl_xor((int)maxk[r], off);
      maxk[r] = maxk[r] > om ? maxk[r] : om;
      unsigned on = (unsigned)__shfl_xor((int)mink[r], off);
      mink[r] = mink[r] < on ? mink[r] : on;
    }
  }

  if (lo == 0) {
    #pragma unroll
    for (int r = 0; r < 16; ++r) {
      int row = rowBase + (r & 3) + 8 * (r >> 2) + 4 * half;
      pmax[split * N + row] = maxk[r];
      pmin[split * N + row] = mink[r];
    }
  }
}

// Kernel 3: combine split keys (u32 max/min), decode indices, recompute ap/an
// in fp32 from ORIGINAL embeddings (matches reference), relu+margin, mean.
__global__ __launch_bounds__(256) void finalize_kernel(
    const float* __restrict__ emb,
    const unsigned* __restrict__ pmax, const unsigned* __restrict__ pmin,
    float* __restrict__ out) {
  int tid = blockIdx.x * 256 + threadIdx.x;   // N*4 threads
  int anchor = tid >> 2;
  int part = tid & 3;
  unsigned Kp = 0u, Kn = 0xFFFFFFFFu;
  #pragma unroll
  for (int s = 0; s < SPLITS; ++s) {
    unsigned vp = pmax[s * N + anchor];
    Kp = Kp > vp ? Kp : vp;
    unsigned vn = pmin[s * N + anchor];
    Kn = Kn < vn ? Kn : vn;
  }
  int jp = 8191 - (int)(Kp & 8191u);
  int jn = (int)(Kn & 8191u);

  const float4* xi = reinterpret_cast<const float4*>(emb + (size_t)anchor * Dq) + part * 4;
  const float4* xp = reinterpret_cast<const float4*>(emb + (size_t)jp * Dq) + part * 4;
  const float4* xn = reinterpret_cast<const float4*>(emb + (size_t)jn * Dq) + part * 4;
  float ap = 0.f, an = 0.f;
  #pragma unroll
  for (int k = 0; k < 4; ++k) {
    float4 a = xi[k], p = xp[k], q = xn[k];
    float dx = a.x - p.x, dy = a.y - p.y, dz = a.z - p.z, dw = a.w - p.w;
    ap += dx * dx + dy * dy + dz * dz + dw * dw;
    dx = a.x - q.x; dy = a.y - q.y; dz = a.z - q.z; dw = a.w - q.w;
    an += dx * dx + dy * dy + dz * dz + dw * dw;
  }
  #pragma unroll
  for (int off = 1; off < 4; off <<= 1) {
    ap += __shfl_xor(ap, off);
    an += __shfl_xor(an, off);
  }
  float loss = (part == 0) ? fmaxf(ap - an + MARGIN, 0.f) : 0.f;
  #pragma unroll
  for (int off = 4; off < 64; off <<= 1) loss += __shfl_xor(loss, off);
  __shared__ float wsum[4];
  if ((threadIdx.x & 63) == 0) wsum[threadIdx.x >> 6] = loss;
  __syncthreads();
  if (threadIdx.x == 0)
    atomicAdd(out, (wsum[0] + wsum[1] + wsum[2] + wsum[3]) * (1.0f / (float)N));
}

extern "C" void kernel_launch(void* const* d_in, const int* in_sizes, int n_in,
                              void* d_out, int out_size, void* d_ws, size_t ws_size,
                              hipStream_t stream) {
  const float* emb = (const float*)d_in[0];
  const int* tgt = (const int*)d_in[1];   // int32 on device (verified R1-R5)
  float* out = (float*)d_out;

  char* ws = (char*)d_ws;
  unsigned short* embF = (unsigned short*)ws;                       // 1 MB tiled bf16
  unsigned short* sqb = (unsigned short*)(ws + (size_t)N * Dq * 2); // 16 KB
  unsigned* pmax = (unsigned*)(ws + (size_t)N * Dq * 2 + N * 2);    // 768 KB
  unsigned* pmin = pmax + (size_t)SPLITS * N;                       // 768 KB

  prep_kernel<<<N * 8 / 256, 256, 0, stream>>>(emb, embF, sqb, out);
  mine_kernel<<<dim3(N / 128, SPLITS), 256, 0, stream>>>(embF, sqb, tgt, pmax, pmin);
  finalize_kernel<<<N * 4 / 256, 256, 0, stream>>>(emb, pmax, pmin, out);
}

// Round 7
// 99.939 us; speedup vs baseline: 2.3667x; 1.2541x over previous
//
#include <hip/hip_runtime.h>
#include <stdint.h>

#define N 8192
#define Dq 64
#define SPLITS 12          // 64*12 = 768 blocks = exactly 3 blocks/CU resident
#define MARGIN 0.5f

typedef __attribute__((ext_vector_type(8))) short short8;     // 8 bf16 (4 VGPRs)
typedef __attribute__((ext_vector_type(16))) float floatx16;  // 32x32 MFMA accumulator

__device__ __forceinline__ unsigned short f2bf(float f) {
  unsigned u = __float_as_uint(f);
  u += 0x7FFF + ((u >> 16) & 1);   // round-to-nearest-even
  return (unsigned short)(u >> 16);
}

// Kernel 1: fp32 -> bf16 convert into FRAGMENT-READY tiled layout + aug-norm
// encode. Layout: embF[tile t][chunk c][lane l] (16B) where lane l gets row
// t*32+(l&31), shorts (l>>5)*8 + c*16 .. +7. A wave's chunk-c fragment load is
// then embF + t*2048 + c*512 + l*8 shorts — perfectly coalesced.
__global__ __launch_bounds__(256) void prep_kernel(
    const float* __restrict__ emb,
    unsigned short* __restrict__ embF, unsigned short* __restrict__ sqb,
    float* __restrict__ out) {
  int tid = blockIdx.x * 256 + threadIdx.x;     // N*8 threads
  int row = tid >> 3;
  int m = tid & 7;                               // chunk-of-8-shorts index
  const float4* src = reinterpret_cast<const float4*>(emb) + (size_t)row * 16 + m * 2;
  float4 v0 = src[0], v1 = src[1];
  float s = v0.x * v0.x + v0.y * v0.y + v0.z * v0.z + v0.w * v0.w
          + v1.x * v1.x + v1.y * v1.y + v1.z * v1.z + v1.w * v1.w;
  #pragma unroll
  for (int off = 1; off < 8; off <<= 1) s += __shfl_xor(s, off);
  if (m == 0) sqb[row] = f2bf(-(0.5f * s + 2.0f));
  short8 b;
  b[0] = (short)f2bf(v0.x); b[1] = (short)f2bf(v0.y);
  b[2] = (short)f2bf(v0.z); b[3] = (short)f2bf(v0.w);
  b[4] = (short)f2bf(v1.x); b[5] = (short)f2bf(v1.y);
  b[6] = (short)f2bf(v1.z); b[7] = (short)f2bf(v1.w);
  // chunk m covers k = m*8..m*8+7  ->  c = m>>1, half = m&1
  size_t dst = (size_t)(row >> 5) * 2048 + (size_t)(m >> 1) * 512
             + (size_t)((m & 1) * 32 + (row & 31)) * 8;
  *reinterpret_cast<short8*>(embF + dst) = b;
  if (tid == 0) out[0] = 0.f;
}

struct TileB {
  short8 b0, b1, b2, b3, b4;
  int cj;
  unsigned j;
};

__device__ __forceinline__ TileB load_tile(const short8* fr,
                                           const unsigned short* sqb,
                                           const int* cls, int t, int lane,
                                           int lo, int half) {
  TileB tb;
  const short8* eb = fr + (size_t)t * 256 + lane;
  tb.b0 = eb[0]; tb.b1 = eb[64]; tb.b2 = eb[128]; tb.b3 = eb[192];
  unsigned short sqn = sqb[t * 32 + lo];
  tb.cj = cls[t * 32 + lo];
  const short one = (short)0x3F80;               // bf16 1.0
  tb.b4 = short8{(short)(half == 0 ? (short)sqn : 0),
                 (short)(half == 0 ? one : 0), 0, 0, 0, 0, 0, 0};
  tb.j = (unsigned)(t * 32 + lo);
  return tb;
}

// Kernel 2: batch-hard mining, 32x32 tiles, fragment-ready coalesced loads,
// TWO candidate tiles in flight per iteration (independent MFMA chains +
// epilogues interleaved -> ~2x per-wave ILP; latency of one chain hides under
// the other's epilogue). acc = dot - 0.5(sq_i+sq_j) - 4 < 0 via 5th augmented
// MFMA; for all-negative floats u32 bits increase monotonically with d, so
// key = (bits(acc)&~0x1FFF)|idx13 gives argmax=u32max, argmin=u32min.
// NOTE: ~130 live unified regs at peak -> bounds(256,3) (~170 budget, no
// spill). bounds(256,6)/R6 and (256,8)/R5 both spilled to scratch (58-390 MB
// FETCH) and regressed badly — do not raise the wave bound on this kernel.
__global__ __launch_bounds__(256, 3) void mine_kernel(
    const unsigned short* __restrict__ embF,
    const unsigned short* __restrict__ sqb, const int* __restrict__ cls,
    unsigned* __restrict__ pmax, unsigned* __restrict__ pmin) {
  const int lane = threadIdx.x & 63;
  const int wave = threadIdx.x >> 6;
  const int lo = lane & 31;
  const int half = lane >> 5;
  const int aT = blockIdx.x * 4 + wave;          // anchor tile 0..255
  const int rowBase = aT * 32;
  const int split = blockIdx.y;
  const int t0 = (256 * split) / SPLITS;
  const int t1 = (256 * (split + 1)) / SPLITS;   // 21 or 22 tiles

  const short8* fr = reinterpret_cast<const short8*>(embF);
  // A fragments: chunk c at fr[tile*256 + c*64 + lane]  (coalesced)
  const short8* ea = fr + (size_t)aT * 256 + lane;
  short8 a0 = ea[0], a1 = ea[64], a2 = ea[128], a3 = ea[192];
  // Aug A frag: A'[m][0]=1.0, A'[m][1]=-(0.5*sq_m+2) (pre-encoded bf16).
  unsigned short sqm = sqb[rowBase + lo];
  const short one = (short)0x3F80;
  short8 a4 = {(short)(half == 0 ? one : 0),
               (short)(half == 0 ? (short)sqm : 0), 0, 0, 0, 0, 0, 0};

  // C/D layout: col = lane&31, row = (reg&3) + 8*(reg>>2) + 4*half.
  int ci[16];
  #pragma unroll
  for (int r = 0; r < 16; ++r)
    ci[r] = cls[rowBase + (r & 3) + 8 * (r >> 2) + 4 * half];

  floatx16 zacc;
  #pragma unroll
  for (int i = 0; i < 16; ++i) zacc[i] = 0.f;

  unsigned maxk[16], mink[16];
  #pragma unroll
  for (int r = 0; r < 16; ++r) { maxk[r] = 0u; mink[r] = 0xFFFFFFFFu; }

  int t = t0;
  for (; t + 1 < t1; t += 2) {
    TileB tA = load_tile(fr, sqb, cls, t, lane, lo, half);
    TileB tB = load_tile(fr, sqb, cls, t + 1, lane, lo, half);

    floatx16 accA = __builtin_amdgcn_mfma_f32_32x32x16_bf16(a0, tA.b0, zacc, 0, 0, 0);
    floatx16 accB = __builtin_amdgcn_mfma_f32_32x32x16_bf16(a0, tB.b0, zacc, 0, 0, 0);
    accA = __builtin_amdgcn_mfma_f32_32x32x16_bf16(a1, tA.b1, accA, 0, 0, 0);
    accB = __builtin_amdgcn_mfma_f32_32x32x16_bf16(a1, tB.b1, accB, 0, 0, 0);
    accA = __builtin_amdgcn_mfma_f32_32x32x16_bf16(a2, tA.b2, accA, 0, 0, 0);
    accB = __builtin_amdgcn_mfma_f32_32x32x16_bf16(a2, tB.b2, accB, 0, 0, 0);
    accA = __builtin_amdgcn_mfma_f32_32x32x16_bf16(a3, tA.b3, accA, 0, 0, 0);
    accB = __builtin_amdgcn_mfma_f32_32x32x16_bf16(a3, tB.b3, accB, 0, 0, 0);
    accA = __builtin_amdgcn_mfma_f32_32x32x16_bf16(a4, tA.b4, accA, 0, 0, 0);
    accB = __builtin_amdgcn_mfma_f32_32x32x16_bf16(a4, tB.b4, accB, 0, 0, 0);

    const unsigned jA = tA.j, jinvA = 8191u - jA;
    const unsigned jB = tB.j, jinvB = 8191u - jB;
    #pragma unroll
    for (int r = 0; r < 16; ++r) {
      unsigned kbA = __float_as_uint(accA[r]) & 0xFFFFE000u;
      bool sameA = (ci[r] == tA.cj);
      unsigned kpA = sameA ? (kbA | jinvA) : 0u;
      unsigned knA = sameA ? 0xFFFFFFFFu : (kbA | jA);
      unsigned kbB = __float_as_uint(accB[r]) & 0xFFFFE000u;
      bool sameB = (ci[r] == tB.cj);
      unsigned kpB = sameB ? (kbB | jinvB) : 0u;
      unsigned knB = sameB ? 0xFFFFFFFFu : (kbB | jB);
      unsigned kp = kpA > kpB ? kpA : kpB;
      unsigned kn = knA < knB ? knA : knB;
      maxk[r] = maxk[r] > kp ? maxk[r] : kp;
      mink[r] = mink[r] < kn ? mink[r] : kn;
    }
  }
  if (t < t1) {   // odd-count tail (21-tile splits)
    TileB tA = load_tile(fr, sqb, cls, t, lane, lo, half);
    floatx16 accA = __builtin_amdgcn_mfma_f32_32x32x16_bf16(a0, tA.b0, zacc, 0, 0, 0);
    accA = __builtin_amdgcn_mfma_f32_32x32x16_bf16(a1, tA.b1, accA, 0, 0, 0);
    accA = __builtin_amdgcn_mfma_f32_32x32x16_bf16(a2, tA.b2, accA, 0, 0, 0);
    accA = __builtin_amdgcn_mfma_f32_32x32x16_bf16(a3, tA.b3, accA, 0, 0, 0);
    accA = __builtin_amdgcn_mfma_f32_32x32x16_bf16(a4, tA.b4, accA, 0, 0, 0);
    const unsigned jA = tA.j, jinvA = 8191u - jA;
    #pragma unroll
    for (int r = 0; r < 16; ++r) {
      unsigned kbA = __float_as_uint(accA[r]) & 0xFFFFE000u;
      bool sameA = (ci[r] == tA.cj);
      unsigned kpA = sameA ? (kbA | jinvA) : 0u;
      unsigned knA = sameA ? 0xFFFFFFFFu : (kbA | jA);
      maxk[r] = maxk[r] > kpA ? maxk[r] : kpA;
      mink[r] = mink[r] < knA ? mink[r] : knA;
    }
  }

  // Column reduction within each 32-lane half (xor masks 1..16 stay in-half).
  #pragma unroll
  for (int off = 1; off < 32; off <<= 1) {
    #pragma unroll
    for (int r = 0; r < 16; ++r) {
      unsigned om = (unsigned)__shfl_xor((int)maxk[r], off);
      maxk[r] = maxk[r] > om ? maxk[r] : om;
      unsigned on = (unsigned)__shfl_xor((int)mink[r], off);
      mink[r] = mink[r] < on ? mink[r] : on;
    }
  }

  if (lo == 0) {
    #pragma unroll
    for (int r = 0; r < 16; ++r) {
      int row = rowBase + (r & 3) + 8 * (r >> 2) + 4 * half;
      pmax[split * N + row] = maxk[r];
      pmin[split * N + row] = mink[r];
    }
  }
}

// Kernel 3: combine split keys (u32 max/min; embedded index makes cross-split
// tie-break automatic), decode indices, recompute ap/an in fp32 from ORIGINAL
// embeddings (matches reference), relu+margin, mean. 4 lanes per anchor.
__global__ __launch_bounds__(256) void finalize_kernel(
    const float* __restrict__ emb,
    const unsigned* __restrict__ pmax, const unsigned* __restrict__ pmin,
    float* __restrict__ out) {
  int tid = blockIdx.x * 256 + threadIdx.x;   // N*4 threads
  int anchor = tid >> 2;
  int part = tid & 3;
  unsigned Kp = 0u, Kn = 0xFFFFFFFFu;
  #pragma unroll
  for (int s = 0; s < SPLITS; ++s) {
    unsigned vp = pmax[s * N + anchor];
    Kp = Kp > vp ? Kp : vp;
    unsigned vn = pmin[s * N + anchor];
    Kn = Kn < vn ? Kn : vn;
  }
  int jp = 8191 - (int)(Kp & 8191u);
  int jn = (int)(Kn & 8191u);

  const float4* xi = reinterpret_cast<const float4*>(emb + (size_t)anchor * Dq) + part * 4;
  const float4* xp = reinterpret_cast<const float4*>(emb + (size_t)jp * Dq) + part * 4;
  const float4* xn = reinterpret_cast<const float4*>(emb + (size_t)jn * Dq) + part * 4;
  float ap = 0.f, an = 0.f;
  #pragma unroll
  for (int k = 0; k < 4; ++k) {
    float4 a = xi[k], p = xp[k], q = xn[k];
    float dx = a.x - p.x, dy = a.y - p.y, dz = a.z - p.z, dw = a.w - p.w;
    ap += dx * dx + dy * dy + dz * dz + dw * dw;
    dx = a.x - q.x; dy = a.y - q.y; dz = a.z - q.z; dw = a.w - q.w;
    an += dx * dx + dy * dy + dz * dz + dw * dw;
  }
  #pragma unroll
  for (int off = 1; off < 4; off <<= 1) {
    ap += __shfl_xor(ap, off);
    an += __shfl_xor(an, off);
  }
  float loss = (part == 0) ? fmaxf(ap - an + MARGIN, 0.f) : 0.f;
  #pragma unroll
  for (int off = 4; off < 64; off <<= 1) loss += __shfl_xor(loss, off);
  __shared__ float wsum[4];
  if ((threadIdx.x & 63) == 0) wsum[threadIdx.x >> 6] = loss;
  __syncthreads();
  if (threadIdx.x == 0)
    atomicAdd(out, (wsum[0] + wsum[1] + wsum[2] + wsum[3]) * (1.0f / (float)N));
}

extern "C" void kernel_launch(void* const* d_in, const int* in_sizes, int n_in,
                              void* d_out, int out_size, void* d_ws, size_t ws_size,
                              hipStream_t stream) {
  const float* emb = (const float*)d_in[0];
  const int* tgt = (const int*)d_in[1];   // int32 on device (verified R1-R6)
  float* out = (float*)d_out;

  char* ws = (char*)d_ws;
  unsigned short* embF = (unsigned short*)ws;                       // 1 MB tiled bf16
  unsigned short* sqb = (unsigned short*)(ws + (size_t)N * Dq * 2); // 16 KB
  unsigned* pmax = (unsigned*)(ws + (size_t)N * Dq * 2 + N * 2);    // 384 KB
  unsigned* pmin = pmax + (size_t)SPLITS * N;                       // 384 KB

  prep_kernel<<<N * 8 / 256, 256, 0, stream>>>(emb, embF, sqb, out);
  mine_kernel<<<dim3(N / 128, SPLITS), 256, 0, stream>>>(embF, sqb, tgt, pmax, pmin);
  finalize_kernel<<<N * 4 / 256, 256, 0, stream>>>(emb, pmax, pmin, out);
}

// Round 9
// 91.974 us; speedup vs baseline: 2.5716x; 1.0866x over previous
//
#include <hip/hip_runtime.h>
#include <stdint.h>

#define N 8192
#define Dq 64
#define SPLITS 16          // 256 cand-tiles / 16 = 16 tiles/split; 64*16=1024 blocks = 4/CU
#define MARGIN 0.5f

typedef __attribute__((ext_vector_type(8))) short short8;     // 8 bf16 (4 VGPRs)
typedef __attribute__((ext_vector_type(16))) float floatx16;  // 32x32 MFMA accumulator

__device__ __forceinline__ unsigned short f2bf(float f) {
  unsigned u = __float_as_uint(f);
  u += 0x7FFF + ((u >> 16) & 1);   // round-to-nearest-even
  return (unsigned short)(u >> 16);
}

// Kernel 0: counting sort of rows by class (128 classes). Single block, 1024
// threads, LDS histogram + serial prefix + LDS-atomic scatter. Scatter order
// within a class is non-deterministic; winners are decided on quantized-d
// keys, and tie-break-by-sorted-position only perturbs within a quantization
// bucket (negligible vs threshold).
__global__ __launch_bounds__(1024) void sort_kernel(
    const int* __restrict__ tgt, int* __restrict__ perm,
    int* __restrict__ clsS, int* __restrict__ base, float* __restrict__ out) {
  __shared__ int hist[128];
  __shared__ int curs[129];
  int tid = threadIdx.x;
  if (tid < 128) hist[tid] = 0;
  __syncthreads();
  int c[8];
  #pragma unroll
  for (int k = 0; k < 8; ++k) {
    c[k] = tgt[tid + 1024 * k];
    atomicAdd(&hist[c[k]], 1);
  }
  __syncthreads();
  if (tid == 0) {
    int run = 0;
    for (int i = 0; i < 128; ++i) { curs[i] = run; run += hist[i]; }
    curs[128] = run;
    out[0] = 0.f;
  }
  __syncthreads();
  if (tid < 129) base[tid] = curs[tid];
  __syncthreads();
  #pragma unroll
  for (int k = 0; k < 8; ++k) {
    int i = tid + 1024 * k;
    int p = atomicAdd(&curs[c[k]], 1);
    perm[p] = i;            // sorted position -> original row
    clsS[p] = c[k];         // class at sorted position
  }
}

// Kernel 1: fp32 -> bf16 convert of PERMUTED rows into fragment-ready tiled
// layout + aug-norm encode bf16(-(0.5*sq+2)). embF[tile][chunk c][lane l]:
// lane l holds sorted-row tile*32+(l&31), shorts (l>>5)*8 + c*16.. — a wave's
// fragment load is perfectly coalesced. One thread per 8 floats.
__global__ __launch_bounds__(256) void prep_kernel(
    const float* __restrict__ emb, const int* __restrict__ perm,
    unsigned short* __restrict__ embF, unsigned short* __restrict__ sqb) {
  int tid = blockIdx.x * 256 + threadIdx.x;     // N*8 threads
  int p = tid >> 3;                              // sorted row
  int m = tid & 7;                               // chunk-of-8-shorts index
  int orig = perm[p];
  const float4* src = reinterpret_cast<const float4*>(emb) + (size_t)orig * 16 + m * 2;
  float4 v0 = src[0], v1 = src[1];
  float s = v0.x * v0.x + v0.y * v0.y + v0.z * v0.z + v0.w * v0.w
          + v1.x * v1.x + v1.y * v1.y + v1.z * v1.z + v1.w * v1.w;
  #pragma unroll
  for (int off = 1; off < 8; off <<= 1) s += __shfl_xor(s, off);
  if (m == 0) sqb[p] = f2bf(-(0.5f * s + 2.0f));
  short8 b;
  b[0] = (short)f2bf(v0.x); b[1] = (short)f2bf(v0.y);
  b[2] = (short)f2bf(v0.z); b[3] = (short)f2bf(v0.w);
  b[4] = (short)f2bf(v1.x); b[5] = (short)f2bf(v1.y);
  b[6] = (short)f2bf(v1.z); b[7] = (short)f2bf(v1.w);
  size_t dst = (size_t)(p >> 5) * 2048 + (size_t)(m >> 1) * 512
             + (size_t)((m & 1) * 32 + (p & 31)) * 8;
  *reinterpret_cast<short8*>(embF + dst) = b;
}

// Kernel 2: batch-hard mining over CLASS-SORTED rows. Anchor tile spans
// classes [c0,c1]; all same-class candidates live in tiles [tLo,tHi]
// (contiguous, ~5 of 256). Pure-negative tiles (everything else): 3-op
// epilogue (and/or/min), no class check, next-tile B-frags prefetched into
// registers. Mixed tiles: full pos+neg epilogue, processed by split 0 only.
// acc = dot-0.5(sq_i+sq_j)-4 < 0 via 5th augmented MFMA; all-negative floats
// are u32-monotone in d, so key=(bits&~0x1FFF)|idx13: argmax=u32max (idx=
// 8191-j -> smaller sorted pos on ties), argmin=u32min (idx=j). Keys carry
// SORTED position j; finalize maps winners through perm[] (R8 bug: it didn't).
// Reg note: ~108 live regs -> bounds(256,4) (128 budget). R5/R6: higher wave
// bounds spill to scratch (58-390 MB FETCH) and regress 2-5x. Keep at 4.
__global__ __launch_bounds__(256, 4) void mine_kernel(
    const unsigned short* __restrict__ embF,
    const unsigned short* __restrict__ sqb, const int* __restrict__ clsS,
    const int* __restrict__ base, const int* __restrict__ perm,
    unsigned* __restrict__ pmax, unsigned* __restrict__ pmin) {
  const int lane = threadIdx.x & 63;
  const int wave = threadIdx.x >> 6;
  const int lo = lane & 31;
  const int half = lane >> 5;
  const int aT = blockIdx.x * 4 + wave;          // anchor tile 0..255
  const int rowBase = aT * 32;
  const int split = blockIdx.y;
  const int s0 = split * (256 / SPLITS);
  const int s1 = s0 + (256 / SPLITS);

  const short8* fr = reinterpret_cast<const short8*>(embF);
  const short8* ea = fr + (size_t)aT * 256 + lane;
  short8 a0 = ea[0], a1 = ea[64], a2 = ea[128], a3 = ea[192];
  unsigned short sqm = sqb[rowBase + lo];
  const short one = (short)0x3F80;               // bf16 1.0
  short8 a4 = {(short)(half == 0 ? one : 0),
               (short)(half == 0 ? (short)sqm : 0), 0, 0, 0, 0, 0, 0};

  const int c0 = clsS[rowBase];
  const int c1 = clsS[rowBase + 31];
  const int tLo = base[c0] >> 5;
  const int tHi = (base[c1 + 1] - 1) >> 5;

  floatx16 zacc;
  #pragma unroll
  for (int i = 0; i < 16; ++i) zacc[i] = 0.f;

  unsigned mink[16];
  #pragma unroll
  for (int r = 0; r < 16; ++r) mink[r] = 0xFFFFFFFFu;

  // ---- pure-negative loop (skips [tLo,tHi]), next-tile register prefetch ----
  auto adv = [&](int t) { return (t >= tLo && t <= tHi) ? (tHi + 1) : t; };
  int tn = adv(s0);
  short8 nb0, nb1, nb2, nb3; unsigned short nsq = 0;
  if (tn < s1) {
    const short8* eb = fr + (size_t)tn * 256 + lane;
    nb0 = eb[0]; nb1 = eb[64]; nb2 = eb[128]; nb3 = eb[192];
    nsq = sqb[tn * 32 + lo];
  }
  while (tn < s1) {
    const int tc = tn;
    short8 cb0 = nb0, cb1 = nb1, cb2 = nb2, cb3 = nb3;
    unsigned short csq = nsq;
    tn = adv(tn + 1);
    if (tn < s1) {                               // prefetch next tile
      const short8* eb = fr + (size_t)tn * 256 + lane;
      nb0 = eb[0]; nb1 = eb[64]; nb2 = eb[128]; nb3 = eb[192];
      nsq = sqb[tn * 32 + lo];
    }
    short8 b4 = {(short)(half == 0 ? (short)csq : 0),
                 (short)(half == 0 ? one : 0), 0, 0, 0, 0, 0, 0};
    floatx16 acc = __builtin_amdgcn_mfma_f32_32x32x16_bf16(a0, cb0, zacc, 0, 0, 0);
    acc = __builtin_amdgcn_mfma_f32_32x32x16_bf16(a1, cb1, acc, 0, 0, 0);
    acc = __builtin_amdgcn_mfma_f32_32x32x16_bf16(a2, cb2, acc, 0, 0, 0);
    acc = __builtin_amdgcn_mfma_f32_32x32x16_bf16(a3, cb3, acc, 0, 0, 0);
    acc = __builtin_amdgcn_mfma_f32_32x32x16_bf16(a4, b4, acc, 0, 0, 0);
    const unsigned j = (unsigned)(tc * 32 + lo);
    #pragma unroll
    for (int r = 0; r < 16; ++r) {
      unsigned kn = (__float_as_uint(acc[r]) & 0xFFFFE000u) | j;
      mink[r] = mink[r] < kn ? mink[r] : kn;
    }
  }

  // ---- mixed tiles [tLo,tHi]: full pos+neg epilogue, split 0 only ----
  unsigned maxk[16];
  #pragma unroll
  for (int r = 0; r < 16; ++r) maxk[r] = 0u;
  if (split == 0) {
    int ci[16];
    #pragma unroll
    for (int r = 0; r < 16; ++r)
      ci[r] = clsS[rowBase + (r & 3) + 8 * (r >> 2) + 4 * half];
    for (int t = tLo; t <= tHi; ++t) {
      const short8* eb = fr + (size_t)t * 256 + lane;
      short8 b0 = eb[0], b1 = eb[64], b2 = eb[128], b3 = eb[192];
      unsigned short sqn = sqb[t * 32 + lo];
      int cj = clsS[t * 32 + lo];
      short8 b4 = {(short)(half == 0 ? (short)sqn : 0),
                   (short)(half == 0 ? one : 0), 0, 0, 0, 0, 0, 0};
      floatx16 acc = __builtin_amdgcn_mfma_f32_32x32x16_bf16(a0, b0, zacc, 0, 0, 0);
      acc = __builtin_amdgcn_mfma_f32_32x32x16_bf16(a1, b1, acc, 0, 0, 0);
      acc = __builtin_amdgcn_mfma_f32_32x32x16_bf16(a2, b2, acc, 0, 0, 0);
      acc = __builtin_amdgcn_mfma_f32_32x32x16_bf16(a3, b3, acc, 0, 0, 0);
      acc = __builtin_amdgcn_mfma_f32_32x32x16_bf16(a4, b4, acc, 0, 0, 0);
      const unsigned j = (unsigned)(t * 32 + lo);
      const unsigned jinv = 8191u - j;
      #pragma unroll
      for (int r = 0; r < 16; ++r) {
        unsigned kb = __float_as_uint(acc[r]) & 0xFFFFE000u;
        bool same = (ci[r] == cj);
        unsigned kp = same ? (kb | jinv) : 0u;
        unsigned kn = same ? 0xFFFFFFFFu : (kb | j);
        maxk[r] = maxk[r] > kp ? maxk[r] : kp;
        mink[r] = mink[r] < kn ? mink[r] : kn;
      }
    }
  }

  // ---- column reduction within each 32-lane half ----
  #pragma unroll
  for (int off = 1; off < 32; off <<= 1) {
    #pragma unroll
    for (int r = 0; r < 16; ++r) {
      unsigned on = (unsigned)__shfl_xor((int)mink[r], off);
      mink[r] = mink[r] < on ? mink[r] : on;
      unsigned om = (unsigned)__shfl_xor((int)maxk[r], off);
      maxk[r] = maxk[r] > om ? maxk[r] : om;
    }
  }

  if (lo == 0) {
    #pragma unroll
    for (int r = 0; r < 16; ++r) {
      int row = rowBase + (r & 3) + 8 * (r >> 2) + 4 * half;  // sorted position
      pmin[split * N + row] = mink[r];
      if (split == 0) pmax[row] = maxk[r];
    }
  }
}

// Kernel 3: combine split mins (u32 keys), decode SORTED winner positions,
// map anchor AND winners through perm[] to original rows (R8 bug: winners
// weren't mapped), recompute ap/an in fp32 from ORIGINAL embeddings (matches
// reference), relu+margin, mean. 4 lanes per anchor.
__global__ __launch_bounds__(256) void finalize_kernel(
    const float* __restrict__ emb, const int* __restrict__ perm,
    const unsigned* __restrict__ pmax, const unsigned* __restrict__ pmin,
    float* __restrict__ out) {
  int tid = blockIdx.x * 256 + threadIdx.x;   // N*4 threads
  int p = tid >> 2;                            // sorted anchor position
  int part = tid & 3;
  unsigned Kn = 0xFFFFFFFFu;
  #pragma unroll
  for (int s = 0; s < SPLITS; ++s) {
    unsigned vn = pmin[s * N + p];
    Kn = Kn < vn ? Kn : vn;
  }
  int jpS = 8191 - (int)(pmax[p] & 8191u);     // sorted hard-positive position
  int jnS = (int)(Kn & 8191u);                 // sorted hard-negative position
  int ai = perm[p];                            // original anchor row
  int jp = perm[jpS];                          // original hard-positive row
  int jn = perm[jnS];                          // original hard-negative row

  const float4* xi = reinterpret_cast<const float4*>(emb + (size_t)ai * Dq) + part * 4;
  const float4* xp = reinterpret_cast<const float4*>(emb + (size_t)jp * Dq) + part * 4;
  const float4* xn = reinterpret_cast<const float4*>(emb + (size_t)jn * Dq) + part * 4;
  float ap = 0.f, an = 0.f;
  #pragma unroll
  for (int k = 0; k < 4; ++k) {
    float4 a = xi[k], q = xp[k], w = xn[k];
    float dx = a.x - q.x, dy = a.y - q.y, dz = a.z - q.z, dw = a.w - q.w;
    ap += dx * dx + dy * dy + dz * dz + dw * dw;
    dx = a.x - w.x; dy = a.y - w.y; dz = a.z - w.z; dw = a.w - w.w;
    an += dx * dx + dy * dy + dz * dz + dw * dw;
  }
  #pragma unroll
  for (int off = 1; off < 4; off <<= 1) {
    ap += __shfl_xor(ap, off);
    an += __shfl_xor(an, off);
  }
  float loss = (part == 0) ? fmaxf(ap - an + MARGIN, 0.f) : 0.f;
  #pragma unroll
  for (int off = 4; off < 64; off <<= 1) loss += __shfl_xor(loss, off);
  __shared__ float wsum[4];
  if ((threadIdx.x & 63) == 0) wsum[threadIdx.x >> 6] = loss;
  __syncthreads();
  if (threadIdx.x == 0)
    atomicAdd(out, (wsum[0] + wsum[1] + wsum[2] + wsum[3]) * (1.0f / (float)N));
}

extern "C" void kernel_launch(void* const* d_in, const int* in_sizes, int n_in,
                              void* d_out, int out_size, void* d_ws, size_t ws_size,
                              hipStream_t stream) {
  const float* emb = (const float*)d_in[0];
  const int* tgt = (const int*)d_in[1];   // int32 on device (verified R1-R8)
  float* out = (float*)d_out;

  char* ws = (char*)d_ws;
  unsigned short* embF = (unsigned short*)(ws + 0);          // 1 MB tiled bf16
  unsigned short* sqb  = (unsigned short*)(ws + 1048576);    // 16 KB
  int* clsS            = (int*)(ws + 1064960);               // 32 KB
  int* perm            = (int*)(ws + 1097728);               // 32 KB
  int* base            = (int*)(ws + 1130496);               // 129 ints (1 KB slot)
  unsigned* pmax       = (unsigned*)(ws + 1131520);          // 32 KB
  unsigned* pmin       = (unsigned*)(ws + 1164288);          // SPLITS*32 KB

  sort_kernel<<<1, 1024, 0, stream>>>(tgt, perm, clsS, base, out);
  prep_kernel<<<N * 8 / 256, 256, 0, stream>>>(emb, perm, embF, sqb);
  mine_kernel<<<dim3(N / 128, SPLITS), 256, 0, stream>>>(embF, sqb, clsS, base,
                                                         perm, pmax, pmin);
  finalize_kernel<<<N * 4 / 256, 256, 0, stream>>>(emb, perm, pmax, pmin, out);
}